// Round 4
// baseline (2317.113 us; speedup 1.0000x reference)
//
#include <hip/hip_runtime.h>
#include <hip/hip_fp16.h>
#include <hip/hip_bf16.h>
#include <float.h>
#include <limits.h>

// Problem constants (fixed by setup_inputs): B=16, L=256, D=128.
#define B_SZ 16
#define L_SZ 256
#define D_SZ 128

// ---------------------------------------------------------------------------
// Kernel 1: pairwise L2 distance (unchanged — not on critical path).
// ---------------------------------------------------------------------------
__global__ __launch_bounds__(256) void dist_kernel(const float* __restrict__ pred,
                                                   const float* __restrict__ target,
                                                   float* __restrict__ dist) {
    __shared__ float predRows[8][D_SZ];
    const int blk = blockIdx.x;
    const int b   = blk >> 5;
    const int i0  = (blk & 31) * 8;
    const int tid = threadIdx.x;

    for (int idx = tid; idx < 8 * D_SZ; idx += 256) {
        int r = idx >> 7, d = idx & (D_SZ - 1);
        predRows[r][d] = pred[((size_t)b * L_SZ + i0 + r) * D_SZ + d];
    }
    __syncthreads();

    const int j = tid;
    const float* tr = target + ((size_t)b * L_SZ + j) * D_SZ;
    float acc[8];
#pragma unroll
    for (int r = 0; r < 8; ++r) acc[r] = 0.0f;

    for (int d = 0; d < D_SZ; d += 4) {
        float4 tv = *(const float4*)(tr + d);
#pragma unroll
        for (int r = 0; r < 8; ++r) {
            float4 pv = *(const float4*)(&predRows[r][d]);
            float dx = pv.x - tv.x; acc[r] += dx * dx;
            float dy = pv.y - tv.y; acc[r] += dy * dy;
            float dz = pv.z - tv.z; acc[r] += dz * dz;
            float dw = pv.w - tv.w; acc[r] += dw * dw;
        }
    }
#pragma unroll
    for (int r = 0; r < 8; ++r)
        dist[((size_t)b * L_SZ + i0 + r) * L_SZ + j] = sqrtf(acc[r]);
}

// ---------------------------------------------------------------------------
// Kernel 2: JV LSA. Init (col reduction + greedy + ARR) as in R3; phase loop
// rebuilt around a single persistent packed word per column:
//   s = (float_bits(d) & 0xFFFFFF00) | column      (d >= 0 => bits sortable)
// settled columns: vshadow = -1e30 so every relax regenerates the identical
// huge packed value -> v_min_u32 can't resurrect, no per-iter masking.
// ---------------------------------------------------------------------------
__device__ inline int readlane_i(int x, int l) { return __builtin_amdgcn_readlane(x, l); }
__device__ inline float readlane_f(float x, int l) {
    return __uint_as_float((unsigned)__builtin_amdgcn_readlane((int)__float_as_uint(x), l));
}
template <int CTRL>
__device__ inline unsigned dpp_umin(unsigned v) {
    unsigned pv = (unsigned)__builtin_amdgcn_update_dpp((int)v, (int)v, CTRL, 0xF, 0xF, false);
    return pv < v ? pv : v;
}
__device__ inline unsigned wave_umin_bcast(unsigned v) {
    v = dpp_umin<0x111>(v);   // row_shr:1
    v = dpp_umin<0x112>(v);   // row_shr:2
    v = dpp_umin<0x114>(v);   // row_shr:4
    v = dpp_umin<0x118>(v);   // row_shr:8
    v = dpp_umin<0x142>(v);   // row_bcast15
    v = dpp_umin<0x143>(v);   // row_bcast31
    return (unsigned)__builtin_amdgcn_readlane((int)v, 63);
}
__device__ inline void unpack4(uint2 pk, float& a, float& b, float& c, float& d) {
    union { unsigned u; __half2 h; } x, y; x.u = pk.x; y.u = pk.y;
    a = __low2float(x.h); b = __high2float(x.h);
    c = __low2float(y.h); d = __high2float(y.h);
}
#define SEL4(a0,a1,a2,a3,k) ((k)==0?(a0):(k)==1?(a1):(k)==2?(a2):(a3))

#define OFF_U      (L_SZ * L_SZ * 2)                 // fp16 matrix: 131072 B
#define OFF_CLAIM  (OFF_U + (L_SZ + 1) * 4)
#define OFF_FL     (OFF_CLAIM + (L_SZ + 1) * 4)
#define LSA_LDS_BYTES (OFF_FL + (L_SZ + 1) * 4 + 4)  // 134160

__global__ __launch_bounds__(64) void lsa_kernel(const float* __restrict__ dist,
                                                 double* __restrict__ partial) {
    extern __shared__ char smem[];
    float* u_lds   = (float*)(smem + OFF_U);
    int*   claimed = (int*)(smem + OFF_CLAIM);
    int*   fl      = (int*)(smem + OFF_FL);

    const int b = blockIdx.x;
    const int t = threadIdx.x;  // 0..63
    const float* cost = dist + (size_t)b * L_SZ * L_SZ;
    const int c0i = 4 * t, c1i = 4 * t + 1, c2i = 4 * t + 2, c3i = 4 * t + 3;

    // ---- stage cost as fp16 in LDS ----
    for (int idx = t * 4; idx < L_SZ * L_SZ; idx += 256) {
        float4 f = *(const float4*)(cost + idx);
        union { unsigned u; __half2 h; } a, c;
        a.h = __floats2half2_rn(f.x, f.y);
        c.h = __floats2half2_rn(f.z, f.w);
        uint2 pk; pk.x = a.u; pk.y = c.u;
        *(uint2*)(smem + idx * 2) = pk;
    }
    __syncthreads();

    // ---- column reduction: v[j] = min_i c[i][j] ----
    float bv0 = FLT_MAX, bv1 = FLT_MAX, bv2 = FLT_MAX, bv3 = FLT_MAX;
    int   br0 = 0, br1 = 0, br2 = 0, br3 = 0;
    for (int i = 1; i <= L_SZ; ++i) {
        uint2 cpk = *(const uint2*)(smem + (size_t)(i - 1) * (L_SZ * 2) + t * 8);
        float c0, c1, c2, c3; unpack4(cpk, c0, c1, c2, c3);
        if (c0 < bv0) { bv0 = c0; br0 = i; }
        if (c1 < bv1) { bv1 = c1; br1 = i; }
        if (c2 < bv2) { bv2 = c2; br2 = i; }
        if (c3 < bv3) { bv3 = c3; br3 = i; }
    }
    float v0 = bv0, v1 = bv1, v2 = bv2, v3 = bv3;

    // ---- greedy tight-edge matching via atomicMin claims ----
    for (int r = t; r <= L_SZ; r += 64) claimed[r] = INT_MAX;
    __syncthreads();
    atomicMin(&claimed[br0], c0i);
    atomicMin(&claimed[br1], c1i);
    atomicMin(&claimed[br2], c2i);
    atomicMin(&claimed[br3], c3i);
    __syncthreads();
    int p0 = (claimed[br0] == c0i) ? br0 : 0;
    int p1 = (claimed[br1] == c1i) ? br1 : 0;
    int p2 = (claimed[br2] == c2i) ? br2 : 0;
    int p3 = (claimed[br3] == c3i) ? br3 : 0;

    // ---- deterministic free-row list (ballot scan) ----
    int nf = 0;
    for (int blk = 0; blk < 4; ++blk) {
        int r = blk * 64 + t + 1;
        bool isfree = (claimed[r] == INT_MAX);
        unsigned long long mask = __ballot(isfree);
        int before = __popcll(mask & ((1ULL << t) - 1ULL));
        if (isfree) fl[nf + before] = r;
        nf += (int)__popcll(mask);
    }
    __syncthreads();

    // ---- augmenting row reduction (lap.cpp, 2 passes, budget-guarded) ----
    int numfree = nf;
    int budget = 1024;
    for (int pass = 0; pass < 2; ++pass) {
        int kq = 0, prv = numfree; numfree = 0;
        while (kq < prv && budget > 0) {
            budget--;
            int i = fl[kq]; kq++;
            uint2 cpk = *(const uint2*)(smem + (size_t)(i - 1) * (L_SZ * 2) + t * 8);
            float cc0, cc1, cc2, cc3; unpack4(cpk, cc0, cc1, cc2, cc3);
            float rc0 = cc0 - v0, rc1 = cc1 - v1, rc2 = cc2 - v2, rc3 = cc3 - v3;
            float m1 = rc0; int j1 = c0i; float m2 = FLT_MAX; int j2 = INT_MAX;
            if (rc1 < m1) { m2 = m1; j2 = j1; m1 = rc1; j1 = c1i; } else if (rc1 < m2) { m2 = rc1; j2 = c1i; }
            if (rc2 < m1) { m2 = m1; j2 = j1; m1 = rc2; j1 = c2i; } else if (rc2 < m2) { m2 = rc2; j2 = c2i; }
            if (rc3 < m1) { m2 = m1; j2 = j1; m1 = rc3; j1 = c3i; } else if (rc3 < m2) { m2 = rc3; j2 = c3i; }
#pragma unroll
            for (int off = 1; off < 64; off <<= 1) {
                float bm1 = __shfl_xor(m1, off, 64); int bj1 = __shfl_xor(j1, off, 64);
                float bm2 = __shfl_xor(m2, off, 64); int bj2 = __shfl_xor(j2, off, 64);
                bool bw = (bm1 < m1) || (bm1 == m1 && bj1 < j1);
                if (bw) {
                    if (bm2 < m1 || (bm2 == m1 && bj2 < j1)) { m2 = bm2; j2 = bj2; }
                    else { m2 = m1; j2 = j1; }
                    m1 = bm1; j1 = bj1;
                } else {
                    if (bm1 < m2 || (bm1 == m2 && bj1 < j2)) { m2 = bm1; j2 = bj1; }
                }
            }
            int t1 = j1 >> 2, k1 = j1 & 3;
            int i0 = readlane_i(SEL4(p0, p1, p2, p3, k1), t1);
            bool strict = (m1 < m2);
            int jt, i0t;
            if (strict) {
                jt = j1; i0t = i0;
                float amt = m2 - m1;
                if (t == t1) {
                    if (k1 == 0) v0 -= amt; else if (k1 == 1) v1 -= amt;
                    else if (k1 == 2) v2 -= amt; else v3 -= amt;
                }
            } else if (i0 != 0) {
                jt = j2; i0t = readlane_i(SEL4(p0, p1, p2, p3, j2 & 3), j2 >> 2);
            } else { jt = j1; i0t = 0; }
            {
                int tt = jt >> 2, kk = jt & 3;
                if (t == tt) {
                    if (kk == 0) p0 = i; else if (kk == 1) p1 = i;
                    else if (kk == 2) p2 = i; else p3 = i;
                }
            }
            if (i0t != 0) {
                if (strict) { kq--; if (t == 0) fl[kq] = i0t; }
                else        { if (t == 0) fl[numfree] = i0t; numfree++; }
            }
            __syncthreads();
        }
        if (budget <= 0) break;
    }

    // ---- rebuild free-row list; init tight duals u ----
    __syncthreads();
    for (int r = t; r <= L_SZ; r += 64) { claimed[r] = 0; u_lds[r] = 0.0f; }
    __syncthreads();
    if (p0) claimed[p0] = 1;
    if (p1) claimed[p1] = 1;
    if (p2) claimed[p2] = 1;
    if (p3) claimed[p3] = 1;
    __syncthreads();
    int nfree = 0;
    for (int blk = 0; blk < 4; ++blk) {
        int r = blk * 64 + t + 1;
        bool isfree = (claimed[r] == 0);
        unsigned long long mask = __ballot(isfree);
        int before = __popcll(mask & ((1ULL << t) - 1ULL));
        if (isfree) fl[nfree + before] = r;
        nfree += (int)__popcll(mask);
    }
    __syncthreads();
    float pu0 = 0.f, pu1 = 0.f, pu2 = 0.f, pu3 = 0.f;
    const __half* ch = (const __half*)smem;
    if (p0) { pu0 = __half2float(ch[(size_t)(p0 - 1) * L_SZ + c0i]) - v0; u_lds[p0] = pu0; }
    if (p1) { pu1 = __half2float(ch[(size_t)(p1 - 1) * L_SZ + c1i]) - v1; u_lds[p1] = pu1; }
    if (p2) { pu2 = __half2float(ch[(size_t)(p2 - 1) * L_SZ + c2i]) - v2; u_lds[p2] = pu2; }
    if (p3) { pu3 = __half2float(ch[(size_t)(p3 - 1) * L_SZ + c3i]) - v3; u_lds[p3] = pu3; }
    __syncthreads();

    // ---- shortest-path phases: packed persistent state ----
    const unsigned HB = __float_as_uint(1e30f) & 0xFFFFFF00u;   // settled marker bits
    const unsigned hp0 = HB | (unsigned)c0i, hp1 = HB | (unsigned)c1i;
    const unsigned hp2 = HB | (unsigned)c2i, hp3 = HB | (unsigned)c3i;
    float vsh0 = v0, vsh1 = v1, vsh2 = v2, vsh3 = v3;   // relax shadow of v

    for (int f = 0; f < nfree; ++f) {
        const int icur = fl[f];
        unsigned s0 = 0x7F7FFF00u | (unsigned)c0i;
        unsigned s1 = 0x7F7FFF00u | (unsigned)c1i;
        unsigned s2 = 0x7F7FFF00u | (unsigned)c2i;
        unsigned s3 = 0x7F7FFF00u | (unsigned)c3i;
        int w0 = -1, w1 = -1, w2 = -1, w3 = -1, um = 0;
        float ds0 = 0.f, ds1 = 0.f, ds2 = 0.f, ds3 = 0.f;
        int   irow = icur;
        float ui0 = u_lds[icur];
        float dj0 = 0.f;
        int   j0  = -1;
        int jS = 0; float dfin = 0.f;

        for (int it = 0; it <= L_SZ; ++it) {
            uint2 cpk = *(const uint2*)(smem + (size_t)(irow - 1) * (L_SZ * 2) + t * 8);
            float cc0, cc1, cc2, cc3; unpack4(cpk, cc0, cc1, cc2, cc3);
            const float base = dj0 - ui0;
            float n0 = fmaxf((cc0 - vsh0) + base, 0.0f);
            float n1 = fmaxf((cc1 - vsh1) + base, 0.0f);
            float n2 = fmaxf((cc2 - vsh2) + base, 0.0f);
            float n3 = fmaxf((cc3 - vsh3) + base, 0.0f);
            unsigned ns0 = (__float_as_uint(n0) & 0xFFFFFF00u) | (unsigned)c0i;
            unsigned ns1 = (__float_as_uint(n1) & 0xFFFFFF00u) | (unsigned)c1i;
            unsigned ns2 = (__float_as_uint(n2) & 0xFFFFFF00u) | (unsigned)c2i;
            unsigned ns3 = (__float_as_uint(n3) & 0xFFFFFF00u) | (unsigned)c3i;
            if (ns0 < s0) w0 = j0;
            if (ns1 < s1) w1 = j0;
            if (ns2 < s2) w2 = j0;
            if (ns3 < s3) w3 = j0;
            s0 = s0 < ns0 ? s0 : ns0;
            s1 = s1 < ns1 ? s1 : ns1;
            s2 = s2 < ns2 ? s2 : ns2;
            s3 = s3 < ns3 ? s3 : ns3;
            unsigned va = s0 < s1 ? s0 : s1;
            unsigned vb = s2 < s3 ? s2 : s3;
            const unsigned pk = wave_umin_bcast(va < vb ? va : vb);
            const int j1 = (int)(pk & 255u);
            const int t1 = j1 >> 2, k1 = j1 & 3;
            const float delta = __uint_as_float(pk & 0xFFFFFF00u);
            int i1; float u1;
            switch (k1) {
                case 0:  i1 = readlane_i(p0, t1); u1 = readlane_f(pu0, t1); break;
                case 1:  i1 = readlane_i(p1, t1); u1 = readlane_f(pu1, t1); break;
                case 2:  i1 = readlane_i(p2, t1); u1 = readlane_f(pu2, t1); break;
                default: i1 = readlane_i(p3, t1); u1 = readlane_f(pu3, t1); break;
            }
            if (i1 == 0 || it == L_SZ) { jS = j1; dfin = delta; break; }
            if (t == t1) {
                switch (k1) {
                    case 0:  s0 = hp0; vsh0 = -1e30f; ds0 = delta; um |= 1; break;
                    case 1:  s1 = hp1; vsh1 = -1e30f; ds1 = delta; um |= 2; break;
                    case 2:  s2 = hp2; vsh2 = -1e30f; ds2 = delta; um |= 4; break;
                    default: s3 = hp3; vsh3 = -1e30f; ds3 = delta; um |= 8; break;
                }
            }
            j0 = j1; dj0 = delta; ui0 = u1; irow = i1;
        }

        // ---- phase end: dual updates (ds_add_f32 via atomicAdd on LDS) ----
        if (um & 1) { atomicAdd(&u_lds[p0], dfin - ds0); v0 += ds0 - dfin; }
        if (um & 2) { atomicAdd(&u_lds[p1], dfin - ds1); v1 += ds1 - dfin; }
        if (um & 4) { atomicAdd(&u_lds[p2], dfin - ds2); v2 += ds2 - dfin; }
        if (um & 8) { atomicAdd(&u_lds[p3], dfin - ds3); v3 += ds3 - dfin; }
        if (t == 0) atomicAdd(&u_lds[icur], dfin);
        vsh0 = v0; vsh1 = v1; vsh2 = v2; vsh3 = v3;

        // ---- augment along way[] ----
        int j = jS;
        for (int st = 0; st <= L_SZ; ++st) {
            int tj = j >> 2, kj = j & 3;
            int jn = readlane_i(SEL4(w0, w1, w2, w3, kj), tj);
            int pn;
            if (jn < 0) pn = icur;
            else pn = readlane_i(SEL4(p0, p1, p2, p3, jn & 3), jn >> 2);
            if (t == tj) {
                if (kj == 0) p0 = pn; else if (kj == 1) p1 = pn;
                else if (kj == 2) p2 = pn; else p3 = pn;
            }
            if (jn < 0) break;
            j = jn;
        }
        __syncthreads();
        pu0 = u_lds[p0]; pu1 = u_lds[p1]; pu2 = u_lds[p2]; pu3 = u_lds[p3];
        __syncthreads();
    }

    // ---- matched sum from ORIGINAL fp32 distances (index-guarded) ----
    double s = 0.0;
    s += (double)cost[(size_t)max(p0 - 1, 0) * L_SZ + c0i];
    s += (double)cost[(size_t)max(p1 - 1, 0) * L_SZ + c1i];
    s += (double)cost[(size_t)max(p2 - 1, 0) * L_SZ + c2i];
    s += (double)cost[(size_t)max(p3 - 1, 0) * L_SZ + c3i];
#pragma unroll
    for (int off = 1; off < 64; off <<= 1) s += __shfl_xor(s, off, 64);
    if (t == 0) partial[b] = s;
}

// ---------------------------------------------------------------------------
// Kernel 3: final mean
// ---------------------------------------------------------------------------
__global__ void finalize_kernel(const double* __restrict__ partial, float* __restrict__ out) {
    double s = 0.0;
    for (int b = 0; b < B_SZ; ++b) s += partial[b];
    out[0] = (float)(s / (double)(B_SZ * L_SZ));
}

extern "C" void kernel_launch(void* const* d_in, const int* in_sizes, int n_in,
                              void* d_out, int out_size, void* d_ws, size_t ws_size,
                              hipStream_t stream) {
    const float* pred   = (const float*)d_in[0];
    const float* target = (const float*)d_in[1];
    float* out = (float*)d_out;

    float*  dist    = (float*)d_ws;
    double* partial = (double*)((char*)d_ws + (size_t)B_SZ * L_SZ * L_SZ * sizeof(float));

    (void)hipFuncSetAttribute((const void*)lsa_kernel,
                              hipFuncAttributeMaxDynamicSharedMemorySize,
                              LSA_LDS_BYTES);

    dist_kernel<<<B_SZ * L_SZ / 8, 256, 0, stream>>>(pred, target, dist);
    lsa_kernel<<<B_SZ, 64, LSA_LDS_BYTES, stream>>>(dist, partial);
    finalize_kernel<<<1, 1, 0, stream>>>(partial, out);
}

// Round 5
// 2170.332 us; speedup vs baseline: 1.0676x; 1.0676x over previous
//
#include <hip/hip_runtime.h>
#include <hip/hip_fp16.h>
#include <hip/hip_bf16.h>
#include <float.h>
#include <limits.h>

// Problem constants (fixed by setup_inputs): B=16, L=256, D=128.
#define B_SZ 16
#define L_SZ 256
#define D_SZ 128

// ---------------------------------------------------------------------------
// Kernel 1: pairwise L2 distance (unchanged — not on critical path).
// ---------------------------------------------------------------------------
__global__ __launch_bounds__(256) void dist_kernel(const float* __restrict__ pred,
                                                   const float* __restrict__ target,
                                                   float* __restrict__ dist) {
    __shared__ float predRows[8][D_SZ];
    const int blk = blockIdx.x;
    const int b   = blk >> 5;
    const int i0  = (blk & 31) * 8;
    const int tid = threadIdx.x;

    for (int idx = tid; idx < 8 * D_SZ; idx += 256) {
        int r = idx >> 7, d = idx & (D_SZ - 1);
        predRows[r][d] = pred[((size_t)b * L_SZ + i0 + r) * D_SZ + d];
    }
    __syncthreads();

    const int j = tid;
    const float* tr = target + ((size_t)b * L_SZ + j) * D_SZ;
    float acc[8];
#pragma unroll
    for (int r = 0; r < 8; ++r) acc[r] = 0.0f;

    for (int d = 0; d < D_SZ; d += 4) {
        float4 tv = *(const float4*)(tr + d);
#pragma unroll
        for (int r = 0; r < 8; ++r) {
            float4 pv = *(const float4*)(&predRows[r][d]);
            float dx = pv.x - tv.x; acc[r] += dx * dx;
            float dy = pv.y - tv.y; acc[r] += dy * dy;
            float dz = pv.z - tv.z; acc[r] += dz * dz;
            float dw = pv.w - tv.w; acc[r] += dw * dw;
        }
    }
#pragma unroll
    for (int r = 0; r < 8; ++r)
        dist[((size_t)b * L_SZ + i0 + r) * L_SZ + j] = sqrtf(acc[r]);
}

// ---------------------------------------------------------------------------
// Kernel 2: JV LSA. R3 init (col reduction + greedy + ARR); phase loop with
// branchless settle, packed delta, pre-tree candidate hoist, min3 tree.
// One batch per block, one wave; lane t owns 0-based columns 4t..4t+3.
// ---------------------------------------------------------------------------
__device__ inline int readlane_i(int x, int l) { return __builtin_amdgcn_readlane(x, l); }
__device__ inline float readlane_f(float x, int l) {
    return __uint_as_float((unsigned)__builtin_amdgcn_readlane((int)__float_as_uint(x), l));
}
__device__ inline unsigned uminu(unsigned a, unsigned b) { return a < b ? a : b; }
template <int CTRL>
__device__ inline unsigned dpp_mov(unsigned v) {
    return (unsigned)__builtin_amdgcn_update_dpp((int)v, (int)v, CTRL, 0xF, 0xF, false);
}
// 5-step min reduce: shr1+shr2 (min3), shr3+shr6 (min3), shr9, bcast15, bcast31.
__device__ inline unsigned wave_umin_bcast(unsigned v) {
    unsigned a = dpp_mov<0x111>(v);
    unsigned b = dpp_mov<0x112>(v);
    v = uminu(uminu(v, a), b);              // covers {i-2..i}
    a = dpp_mov<0x113>(v);
    b = dpp_mov<0x116>(v);
    v = uminu(uminu(v, a), b);              // covers {i-8..i}
    a = dpp_mov<0x119>(v);
    v = uminu(v, a);                        // lane15 of each row: full row
    a = dpp_mov<0x142>(v);                  // row_bcast15
    v = uminu(v, a);
    a = dpp_mov<0x143>(v);                  // row_bcast31
    v = uminu(v, a);
    return (unsigned)__builtin_amdgcn_readlane((int)v, 63);
}
__device__ inline void unpack4(uint2 pk, float& a, float& b, float& c, float& d) {
    union { unsigned u; __half2 h; } x, y; x.u = pk.x; y.u = pk.y;
    a = __low2float(x.h); b = __high2float(x.h);
    c = __low2float(y.h); d = __high2float(y.h);
}
#define SEL4(a0,a1,a2,a3,k) ((k)==0?(a0):(k)==1?(a1):(k)==2?(a2):(a3))

#define OFF_U      (L_SZ * L_SZ * 2)                 // fp16 matrix: 131072 B
#define OFF_CLAIM  (OFF_U + (L_SZ + 1) * 4)
#define OFF_FL     (OFF_CLAIM + (L_SZ + 1) * 4)
#define LSA_LDS_BYTES (OFF_FL + (L_SZ + 1) * 4 + 4)  // 134160

__global__ __launch_bounds__(64) void lsa_kernel(const float* __restrict__ dist,
                                                 double* __restrict__ partial) {
    extern __shared__ char smem[];
    float* u_lds   = (float*)(smem + OFF_U);
    int*   claimed = (int*)(smem + OFF_CLAIM);
    int*   fl      = (int*)(smem + OFF_FL);

    const int b = blockIdx.x;
    const int t = threadIdx.x;  // 0..63
    const float* cost = dist + (size_t)b * L_SZ * L_SZ;
    const int c0i = 4 * t, c1i = 4 * t + 1, c2i = 4 * t + 2, c3i = 4 * t + 3;

    // ---- stage cost as fp16 in LDS ----
    for (int idx = t * 4; idx < L_SZ * L_SZ; idx += 256) {
        float4 f = *(const float4*)(cost + idx);
        union { unsigned u; __half2 h; } a, c;
        a.h = __floats2half2_rn(f.x, f.y);
        c.h = __floats2half2_rn(f.z, f.w);
        uint2 pk; pk.x = a.u; pk.y = c.u;
        *(uint2*)(smem + idx * 2) = pk;
    }
    __syncthreads();

    // ---- column reduction: v[j] = min_i c[i][j] ----
    float bv0 = FLT_MAX, bv1 = FLT_MAX, bv2 = FLT_MAX, bv3 = FLT_MAX;
    int   br0 = 0, br1 = 0, br2 = 0, br3 = 0;
    for (int i = 1; i <= L_SZ; ++i) {
        uint2 cpk = *(const uint2*)(smem + (size_t)(i - 1) * (L_SZ * 2) + t * 8);
        float c0, c1, c2, c3; unpack4(cpk, c0, c1, c2, c3);
        if (c0 < bv0) { bv0 = c0; br0 = i; }
        if (c1 < bv1) { bv1 = c1; br1 = i; }
        if (c2 < bv2) { bv2 = c2; br2 = i; }
        if (c3 < bv3) { bv3 = c3; br3 = i; }
    }
    float v0 = bv0, v1 = bv1, v2 = bv2, v3 = bv3;

    // ---- greedy tight-edge matching via atomicMin claims ----
    for (int r = t; r <= L_SZ; r += 64) claimed[r] = INT_MAX;
    __syncthreads();
    atomicMin(&claimed[br0], c0i);
    atomicMin(&claimed[br1], c1i);
    atomicMin(&claimed[br2], c2i);
    atomicMin(&claimed[br3], c3i);
    __syncthreads();
    int p0 = (claimed[br0] == c0i) ? br0 : 0;
    int p1 = (claimed[br1] == c1i) ? br1 : 0;
    int p2 = (claimed[br2] == c2i) ? br2 : 0;
    int p3 = (claimed[br3] == c3i) ? br3 : 0;

    // ---- deterministic free-row list (ballot scan) ----
    int nf = 0;
    for (int blk = 0; blk < 4; ++blk) {
        int r = blk * 64 + t + 1;
        bool isfree = (claimed[r] == INT_MAX);
        unsigned long long mask = __ballot(isfree);
        int before = __popcll(mask & ((1ULL << t) - 1ULL));
        if (isfree) fl[nf + before] = r;
        nf += (int)__popcll(mask);
    }
    __syncthreads();

    // ---- augmenting row reduction (lap.cpp, 2 passes, budget-guarded) ----
    int numfree = nf;
    int budget = 1024;
    for (int pass = 0; pass < 2; ++pass) {
        int kq = 0, prv = numfree; numfree = 0;
        while (kq < prv && budget > 0) {
            budget--;
            int i = fl[kq]; kq++;
            uint2 cpk = *(const uint2*)(smem + (size_t)(i - 1) * (L_SZ * 2) + t * 8);
            float cc0, cc1, cc2, cc3; unpack4(cpk, cc0, cc1, cc2, cc3);
            float rc0 = cc0 - v0, rc1 = cc1 - v1, rc2 = cc2 - v2, rc3 = cc3 - v3;
            float m1 = rc0; int j1 = c0i; float m2 = FLT_MAX; int j2 = INT_MAX;
            if (rc1 < m1) { m2 = m1; j2 = j1; m1 = rc1; j1 = c1i; } else if (rc1 < m2) { m2 = rc1; j2 = c1i; }
            if (rc2 < m1) { m2 = m1; j2 = j1; m1 = rc2; j1 = c2i; } else if (rc2 < m2) { m2 = rc2; j2 = c2i; }
            if (rc3 < m1) { m2 = m1; j2 = j1; m1 = rc3; j1 = c3i; } else if (rc3 < m2) { m2 = rc3; j2 = c3i; }
#pragma unroll
            for (int off = 1; off < 64; off <<= 1) {
                float bm1 = __shfl_xor(m1, off, 64); int bj1 = __shfl_xor(j1, off, 64);
                float bm2 = __shfl_xor(m2, off, 64); int bj2 = __shfl_xor(j2, off, 64);
                bool bw = (bm1 < m1) || (bm1 == m1 && bj1 < j1);
                if (bw) {
                    if (bm2 < m1 || (bm2 == m1 && bj2 < j1)) { m2 = bm2; j2 = bj2; }
                    else { m2 = m1; j2 = j1; }
                    m1 = bm1; j1 = bj1;
                } else {
                    if (bm1 < m2 || (bm1 == m2 && bj1 < j2)) { m2 = bm1; j2 = bj1; }
                }
            }
            int t1 = j1 >> 2, k1 = j1 & 3;
            int i0 = readlane_i(SEL4(p0, p1, p2, p3, k1), t1);
            bool strict = (m1 < m2);
            int jt, i0t;
            if (strict) {
                jt = j1; i0t = i0;
                float amt = m2 - m1;
                if (t == t1) {
                    if (k1 == 0) v0 -= amt; else if (k1 == 1) v1 -= amt;
                    else if (k1 == 2) v2 -= amt; else v3 -= amt;
                }
            } else if (i0 != 0) {
                jt = j2; i0t = readlane_i(SEL4(p0, p1, p2, p3, j2 & 3), j2 >> 2);
            } else { jt = j1; i0t = 0; }
            {
                int tt = jt >> 2, kk = jt & 3;
                if (t == tt) {
                    if (kk == 0) p0 = i; else if (kk == 1) p1 = i;
                    else if (kk == 2) p2 = i; else p3 = i;
                }
            }
            if (i0t != 0) {
                if (strict) { kq--; if (t == 0) fl[kq] = i0t; }
                else        { if (t == 0) fl[numfree] = i0t; numfree++; }
            }
            __syncthreads();
        }
        if (budget <= 0) break;
    }

    // ---- rebuild free-row list; init tight duals u ----
    __syncthreads();
    for (int r = t; r <= L_SZ; r += 64) { claimed[r] = 0; u_lds[r] = 0.0f; }
    __syncthreads();
    if (p0) claimed[p0] = 1;
    if (p1) claimed[p1] = 1;
    if (p2) claimed[p2] = 1;
    if (p3) claimed[p3] = 1;
    __syncthreads();
    int nfree = 0;
    for (int blk = 0; blk < 4; ++blk) {
        int r = blk * 64 + t + 1;
        bool isfree = (claimed[r] == 0);
        unsigned long long mask = __ballot(isfree);
        int before = __popcll(mask & ((1ULL << t) - 1ULL));
        if (isfree) fl[nfree + before] = r;
        nfree += (int)__popcll(mask);
    }
    __syncthreads();
    float pu0 = 0.f, pu1 = 0.f, pu2 = 0.f, pu3 = 0.f;
    const __half* ch = (const __half*)smem;
    if (p0) { pu0 = __half2float(ch[(size_t)(p0 - 1) * L_SZ + c0i]) - v0; u_lds[p0] = pu0; }
    if (p1) { pu1 = __half2float(ch[(size_t)(p1 - 1) * L_SZ + c1i]) - v1; u_lds[p1] = pu1; }
    if (p2) { pu2 = __half2float(ch[(size_t)(p2 - 1) * L_SZ + c2i]) - v2; u_lds[p2] = pu2; }
    if (p3) { pu3 = __half2float(ch[(size_t)(p3 - 1) * L_SZ + c3i]) - v3; u_lds[p3] = pu3; }
    __syncthreads();

    // ---- shortest-path phases ----
    const unsigned HB  = __float_as_uint(1e30f) & 0xFFFFFF00u;   // settled marker
    const unsigned hp0 = HB | (unsigned)c0i, hp1 = HB | (unsigned)c1i;
    const unsigned hp2 = HB | (unsigned)c2i, hp3 = HB | (unsigned)c3i;
    float vsh0 = v0, vsh1 = v1, vsh2 = v2, vsh3 = v3;   // relax shadow of v

    for (int f = 0; f < nfree; ++f) {
        const int icur = fl[f];
        unsigned s0 = 0x7F7FFF00u | (unsigned)c0i;
        unsigned s1 = 0x7F7FFF00u | (unsigned)c1i;
        unsigned s2 = 0x7F7FFF00u | (unsigned)c2i;
        unsigned s3 = 0x7F7FFF00u | (unsigned)c3i;
        int w0 = -1, w1 = -1, w2 = -1, w3 = -1;
        float ds0 = 0.f, ds1 = 0.f, ds2 = 0.f, ds3 = 0.f;
        int   irow = icur;
        float ui0 = u_lds[icur];
        float dj0 = 0.f;
        int   j0  = -1;
        int jS = 0; float dfin = 0.f;

        for (int it = 0; it <= L_SZ; ++it) {
            // relax all columns from row irow
            uint2 cpk = *(const uint2*)(smem + (size_t)(irow - 1) * (L_SZ * 2) + t * 8);
            float cc0, cc1, cc2, cc3; unpack4(cpk, cc0, cc1, cc2, cc3);
            const float base = dj0 - ui0;
            float n0 = fmaxf((cc0 - vsh0) + base, 0.0f);
            float n1 = fmaxf((cc1 - vsh1) + base, 0.0f);
            float n2 = fmaxf((cc2 - vsh2) + base, 0.0f);
            float n3 = fmaxf((cc3 - vsh3) + base, 0.0f);
            unsigned np0 = (__float_as_uint(n0) & 0xFFFFFF00u) | (unsigned)c0i;
            unsigned np1 = (__float_as_uint(n1) & 0xFFFFFF00u) | (unsigned)c1i;
            unsigned np2 = (__float_as_uint(n2) & 0xFFFFFF00u) | (unsigned)c2i;
            unsigned np3 = (__float_as_uint(n3) & 0xFFFFFF00u) | (unsigned)c3i;
            bool b0 = np0 < s0, b1 = np1 < s1, b2 = np2 < s2, b3 = np3 < s3;
            w0 = b0 ? j0 : w0;  s0 = b0 ? np0 : s0;
            w1 = b1 ? j0 : w1;  s1 = b1 ? np1 : s1;
            w2 = b2 ? j0 : w2;  s2 = b2 ? np2 : s2;
            w3 = b3 ? j0 : w3;  s3 = b3 ? np3 : s3;

            // per-lane min4 + candidate hoist (parallel with tree)
            unsigned m01 = uminu(s0, s1), m23 = uminu(s2, s3);
            unsigned m4  = uminu(m01, m23);
            int kloc = (int)(m4 & 3u);
            int   myi = SEL4(p0, p1, p2, p3, kloc);
            float myu = SEL4(pu0, pu1, pu2, pu3, kloc);

            const unsigned pk = wave_umin_bcast(m4);
            const int   j1    = (int)(pk & 255u);
            const int   t1    = j1 >> 2;
            const float delta = __uint_as_float(pk & 0xFFFFFF00u);
            const int   i1    = readlane_i(myi, t1);
            const float u1    = readlane_f(myu, t1);

            if (i1 == 0 || it == L_SZ) { jS = j1; dfin = delta; break; }

            // branchless settle of column j1
            bool e0 = (c0i == j1), e1 = (c1i == j1), e2 = (c2i == j1), e3 = (c3i == j1);
            vsh0 = e0 ? -1e30f : vsh0;  s0 = e0 ? hp0 : s0;  ds0 = e0 ? delta : ds0;
            vsh1 = e1 ? -1e30f : vsh1;  s1 = e1 ? hp1 : s1;  ds1 = e1 ? delta : ds1;
            vsh2 = e2 ? -1e30f : vsh2;  s2 = e2 ? hp2 : s2;  ds2 = e2 ? delta : ds2;
            vsh3 = e3 ? -1e30f : vsh3;  s3 = e3 ? hp3 : s3;  ds3 = e3 ? delta : ds3;

            j0 = j1; dj0 = delta; ui0 = u1; irow = i1;
        }

        // ---- phase end: dual updates (settled test: vsh sentinel) ----
        if (vsh0 < -1e29f) { u_lds[p0] += dfin - ds0; v0 += ds0 - dfin; }
        if (vsh1 < -1e29f) { u_lds[p1] += dfin - ds1; v1 += ds1 - dfin; }
        if (vsh2 < -1e29f) { u_lds[p2] += dfin - ds2; v2 += ds2 - dfin; }
        if (vsh3 < -1e29f) { u_lds[p3] += dfin - ds3; v3 += ds3 - dfin; }
        if (t == 0) u_lds[icur] += dfin;
        vsh0 = v0; vsh1 = v1; vsh2 = v2; vsh3 = v3;
        __syncthreads();

        // ---- augment along way[] ----
        int j = jS;
        for (int st = 0; st <= L_SZ; ++st) {
            int tj = j >> 2, kj = j & 3;
            int jn = readlane_i(SEL4(w0, w1, w2, w3, kj), tj);
            int pn;
            if (jn < 0) pn = icur;
            else pn = readlane_i(SEL4(p0, p1, p2, p3, jn & 3), jn >> 2);
            if (t == tj) {
                if (kj == 0) p0 = pn; else if (kj == 1) p1 = pn;
                else if (kj == 2) p2 = pn; else p3 = pn;
            }
            if (jn < 0) break;
            j = jn;
        }
        __syncthreads();
        pu0 = u_lds[p0]; pu1 = u_lds[p1]; pu2 = u_lds[p2]; pu3 = u_lds[p3];
        __syncthreads();
    }

    // ---- matched sum from ORIGINAL fp32 distances (index-guarded) ----
    double s = 0.0;
    s += (double)cost[(size_t)max(p0 - 1, 0) * L_SZ + c0i];
    s += (double)cost[(size_t)max(p1 - 1, 0) * L_SZ + c1i];
    s += (double)cost[(size_t)max(p2 - 1, 0) * L_SZ + c2i];
    s += (double)cost[(size_t)max(p3 - 1, 0) * L_SZ + c3i];
#pragma unroll
    for (int off = 1; off < 64; off <<= 1) s += __shfl_xor(s, off, 64);
    if (t == 0) partial[b] = s;
}

// ---------------------------------------------------------------------------
// Kernel 3: final mean
// ---------------------------------------------------------------------------
__global__ void finalize_kernel(const double* __restrict__ partial, float* __restrict__ out) {
    double s = 0.0;
    for (int b = 0; b < B_SZ; ++b) s += partial[b];
    out[0] = (float)(s / (double)(B_SZ * L_SZ));
}

extern "C" void kernel_launch(void* const* d_in, const int* in_sizes, int n_in,
                              void* d_out, int out_size, void* d_ws, size_t ws_size,
                              hipStream_t stream) {
    const float* pred   = (const float*)d_in[0];
    const float* target = (const float*)d_in[1];
    float* out = (float*)d_out;

    float*  dist    = (float*)d_ws;
    double* partial = (double*)((char*)d_ws + (size_t)B_SZ * L_SZ * L_SZ * sizeof(float));

    (void)hipFuncSetAttribute((const void*)lsa_kernel,
                              hipFuncAttributeMaxDynamicSharedMemorySize,
                              LSA_LDS_BYTES);

    dist_kernel<<<B_SZ * L_SZ / 8, 256, 0, stream>>>(pred, target, dist);
    lsa_kernel<<<B_SZ, 64, LSA_LDS_BYTES, stream>>>(dist, partial);
    finalize_kernel<<<1, 1, 0, stream>>>(partial, out);
}